// Round 12
// baseline (45.309 us; speedup 1.0000x reference)
//
#include <hip/hip_runtime.h>
#include <hip/hip_bf16.h>

// Problem constants (fixed by the reference file):
//   B=16 docs, PREV(K)=768, D(N)=256, lengths[i]=1024+128*i, T=31744, MAXLEN=2944
// All lengths and doc start offsets are multiples of 128 -> 128-row M-tiles
// never straddle docs. Per-doc padding is a multiple of 64.

#define T_TOTAL 31744
#define K_DIM   768
#define N_DIM   256
#define MAXLEN  2944
#define NKT     24          // K_DIM / 32
#define NGEMM   248         // T_TOTAL / 128  (<= 256 CUs: one parallel wave)
#define NZERO   240         // 15360 padding rows / 64

typedef __attribute__((ext_vector_type(8))) short    bf16x8;
typedef __attribute__((ext_vector_type(4))) float    f32x4;
typedef __attribute__((ext_vector_type(4))) unsigned u32x4;

__device__ __forceinline__ unsigned short f2bf(float f) {
  unsigned u = __builtin_bit_cast(unsigned, f);
  u += 0x7fffu + ((u >> 16) & 1u);
  return (unsigned short)(u >> 16);
}

__device__ __forceinline__ unsigned cvtpk(float lo, float hi) {
  unsigned r;
  asm("v_cvt_pk_bf16_f32 %0, %1, %2" : "=v"(r) : "v"(lo), "v"(hi));
  return r;
}

// async global->LDS, 16B per lane; LDS dest = wave-uniform base + lane*16
__device__ __forceinline__ void gload16(const void* g, void* l) {
  __builtin_amdgcn_global_load_lds(
      (const __attribute__((address_space(1))) unsigned int*)g,
      (__attribute__((address_space(3))) unsigned int*)l,
      16, 0, 0);
}

// ---------------------------------------------------------------------------
// Kernel 1: W [768][256] f32 -> Wt_tiled bf16 in EXACT per-K-step LDS image
// order: element (kt, h, col, e) = bf16(W[kt*32 + h*8 + e][col]).
// GEMM staging of B is then a contiguous 16KB copy per K-step.
// ---------------------------------------------------------------------------
__global__ __launch_bounds__(256) void wt_tile(const float* __restrict__ W,
                                               unsigned short* __restrict__ Wt) {
  __shared__ float Wl[32][257];     // +1 pad
  const int kt  = blockIdx.x;       // 0..23
  const int tid = threadIdx.x;

#pragma unroll
  for (int i = 0; i < 8; ++i) {
    const int idx = i * 256 + tid;          // 0..2047 chunks of f32x4
    const int row = idx >> 6;
    const int c4  = idx & 63;
    f32x4 v = *(const f32x4*)(W + (size_t)(kt * 32 + row) * N_DIM + c4 * 4);
    Wl[row][c4 * 4 + 0] = v[0];
    Wl[row][c4 * 4 + 1] = v[1];
    Wl[row][c4 * 4 + 2] = v[2];
    Wl[row][c4 * 4 + 3] = v[3];
  }
  __syncthreads();

#pragma unroll
  for (int h = 0; h < 4; ++h) {
    bf16x8 ov;
#pragma unroll
    for (int e = 0; e < 8; ++e) ov[e] = (short)f2bf(Wl[h * 8 + e][tid]);
    *(bf16x8*)(Wt + (((size_t)kt * 4 + h) * 256 + tid) * 8) = ov;
  }
}

// ---------------------------------------------------------------------------
// Kernel 2: GEMM + scatter + fused padding zero-fill.
//   blocks [0, 248):   BM=128 GEMM tile — 248 blocks <= 256 CUs, so the whole
//                      GEMM runs as ONE parallel wave of blocks (R8-R11 were
//                      serial-block-limited: ~2-4 sequential blocks/CU).
//   blocks [248, 488): zero 64 padding rows each (write-only, co-resident)
//
// LDS 48KB/block (A 2x8KB bf16 + B 2x16KB bf16) -> 2 blocks/CU resident.
//   A image: slot16 = g*128 + (row ^ 2g), g = k-octet. Stage: thread t ->
//     row=t>>2, g=t&3: 32B coalesced f32 read (4 thr/row), cvt_pk,
//     ds_write_b128 (4x256B permuted windows: conflict-free).
//     Frag read: abase + mf*256 (XOR confined to low 4 bits: contiguous
//     permuted 256B per 16 lanes: conflict-free).
//   B image: contiguous 16KB DMA from Wt_tiled (proven R6/R8 map).
// 512 threads = 8 waves (2m x 4n); per-wave 64x64 tile (4x4 frags, acc 64).
// ---------------------------------------------------------------------------
__global__ __launch_bounds__(512, 2) void gemm_scatter(const float* __restrict__ A,
                                                       const unsigned short* __restrict__ Wt,
                                                       const float* __restrict__ bias,
                                                       float* __restrict__ out) {
  const int tid = threadIdx.x;

  // ---------------- fused zero-fill blocks ----------------
  if (blockIdx.x >= NGEMM) {
    const int z  = blockIdx.x - NGEMM;   // 0..239
    const int p0 = z * 64;               // global padding-row index
    int d = 0, c = 0;
    while (d < 15) {
      const int pad = 1920 - 128 * d;
      if (p0 < c + pad) break;
      c += pad; ++d;
    }
    const int len = 1024 + 128 * d;
    const size_t row0 = (size_t)d * MAXLEN + len + (p0 - c);
    float* dst = out + row0 * N_DIM;
    const f32x4 z4 = {0.f, 0.f, 0.f, 0.f};
#pragma unroll
    for (int j = 0; j < 8; ++j)
      *(f32x4*)(dst + (size_t)(j * 512 + tid) * 4) = z4;
    return;
  }

  // ---------------- GEMM blocks ----------------
  __shared__ f32x4 AbV[2][512];    // 2 x 8KB  bf16 A images
  __shared__ f32x4 BbV[2][1024];   // 2 x 16KB bf16 B images

  const int wid  = tid >> 6;
  const int lane = tid & 63;
  const int l15  = lane & 15;
  const int l4   = lane >> 4;
  const int wr   = wid >> 2;     // 0..1  (M half: 64 rows)
  const int wc   = wid & 3;      // 0..3  (N quarter: 64 cols)
  const int t0   = blockIdx.x * 128;

  // which doc does this tile live in (tiles never straddle docs)
  int off = 0, doc = 0;
  while (doc < 15) {
    const int len = 1024 + 128 * doc;
    if (t0 < off + len) break;
    off += len; ++doc;
  }
  const long tgt0 = (long)doc * MAXLEN + (t0 - off);

  // ---- A stage: thread t -> row = t>>2 (0..127), g = t&3 (k-octet) ----
  const int rowS = tid >> 2;
  const int gS   = tid & 3;
  const float* pA = A + (size_t)(t0 + rowS) * K_DIM + gS * 8;
  const int awbyte = (gS * 128 + (rowS ^ (gS << 1))) * 16;   // XOR-permuted slot

  // ---- B DMA source (contiguous 16KB per K-step, 2 sweeps of 8KB) ----
  const unsigned short* pB = Wt + (size_t)tid * 8;

  char* ldsA  = (char*)&AbV[0][0];
  char* ldsB  = (char*)&BbV[0][0];
  char* ldsBw = ldsB + wid * 1024;

  // ---- fragment read offsets ----
  const int arowb = wr * 64 + l15;
  const int abase = (l4 * 128 + (arowb ^ (l4 << 1))) * 16;   // + mf*256
  const int boff  = l4 * 4096 + (wc * 64 + l15) * 16;        // + nf*256

  f32x4 acc[4][4];
#pragma unroll
  for (int m = 0; m < 4; ++m)
#pragma unroll
    for (int n = 0; n < 4; ++n) acc[m][n] = f32x4{0.f, 0.f, 0.f, 0.f};

#define LOAD_A(t_, La0, La1)                                             \
  {                                                                      \
    La0 = *(const f32x4*)(pA + (t_) * 32);                               \
    La1 = *(const f32x4*)(pA + (t_) * 32 + 4);                           \
  }
#define WRITE_A(buf, La0, La1)                                           \
  {                                                                      \
    u32x4 u;                                                             \
    u[0] = cvtpk(La0[0], La0[1]); u[1] = cvtpk(La0[2], La0[3]);          \
    u[2] = cvtpk(La1[0], La1[1]); u[3] = cvtpk(La1[2], La1[3]);          \
    *(u32x4*)(ldsA + (buf) * 8192 + awbyte) = u;                         \
  }
#define STAGE_B(buf, kt_)                                                \
  {                                                                      \
    gload16(pB + (size_t)(kt_) * 8192, ldsBw + (buf) * 16384);           \
    gload16(pB + (size_t)(kt_) * 8192 + 4096,                            \
            ldsBw + (buf) * 16384 + 8192);                               \
  }

#define COMPUTE(buf)                                                     \
  {                                                                      \
    const char* ab = ldsA + (buf) * 8192 + abase;                        \
    const char* bb = ldsB + (buf) * 16384 + boff;                        \
    bf16x8 bfr[4], afr[4];                                               \
    _Pragma("unroll") for (int n = 0; n < 4; ++n)                        \
      bfr[n] = *(const bf16x8*)(bb + n * 256);                           \
    _Pragma("unroll") for (int m = 0; m < 4; ++m)                        \
      afr[m] = *(const bf16x8*)(ab + m * 256);                           \
    _Pragma("unroll") for (int m = 0; m < 4; ++m)                        \
      _Pragma("unroll") for (int n = 0; n < 4; ++n)                      \
        acc[m][n] = __builtin_amdgcn_mfma_f32_16x16x32_bf16(afr[m], bfr[n], \
                                                            acc[m][n], 0, 0, 0); \
  }

  // prologue: stage tile 0, barrier
  {
    f32x4 La0, La1;
    LOAD_A(0, La0, La1)
    STAGE_B(0, 0)
    WRITE_A(0, La0, La1)
  }
  __syncthreads();

  // main loop: loads(t+1) issued first, compute(t) covers them, write, barrier
#pragma unroll 1
  for (int t = 0; t < NKT - 1; ++t) {
    f32x4 La0, La1;
    LOAD_A(t + 1, La0, La1)
    STAGE_B((t + 1) & 1, t + 1)
    COMPUTE(t & 1)
    WRITE_A((t + 1) & 1, La0, La1)
    __syncthreads();
  }
  COMPUTE((NKT - 1) & 1)

  // epilogue: bias + scatter to padded rows
  float bc[4];
#pragma unroll
  for (int n = 0; n < 4; ++n) bc[n] = bias[wc * 64 + n * 16 + l15];

#pragma unroll
  for (int m = 0; m < 4; ++m)
#pragma unroll
    for (int n = 0; n < 4; ++n) {
      const size_t base = (size_t)(tgt0 + wr * 64 + m * 16 + l4 * 4) * N_DIM
                        + wc * 64 + n * 16 + l15;
#pragma unroll
      for (int j = 0; j < 4; ++j)
        out[base + (size_t)j * N_DIM] = acc[m][n][j] + bc[n];
    }
#undef LOAD_A
#undef WRITE_A
#undef STAGE_B
#undef COMPUTE
}

// ---------------------------------------------------------------------------
extern "C" void kernel_launch(void* const* d_in, const int* in_sizes, int n_in,
                              void* d_out, int out_size, void* d_ws, size_t ws_size,
                              hipStream_t stream) {
  const float* A    = (const float*)d_in[0];   // [31744, 768]
  const float* W    = (const float*)d_in[1];   // [768, 256]
  const float* bias = (const float*)d_in[2];   // [256]
  float* out = (float*)d_out;                  // [16, 2944, 256]
  unsigned short* Wt = (unsigned short*)d_ws;  // Wt_tiled bf16 [24][4][256][8]

  wt_tile<<<24, 256, 0, stream>>>(W, Wt);
  gemm_scatter<<<NGEMM + NZERO, 512, 0, stream>>>(A, Wt, bias, out);
}

// Round 13
// 34.798 us; speedup vs baseline: 1.3021x; 1.3021x over previous
//
#include <hip/hip_runtime.h>
#include <hip/hip_bf16.h>

// Problem constants (fixed by the reference file):
//   B=16 docs, PREV(K)=768, D(N)=256, lengths[i]=1024+128*i, T=31744, MAXLEN=2944
// Doc start offsets are multiples of 128 -> 64-row M-tiles never straddle docs.
// Per-doc padding 1920-128*d is a multiple of 64 -> 64-row zero tiles never straddle.

#define T_TOTAL 31744
#define K_DIM   768
#define N_DIM   256
#define MAXLEN  2944
#define NKT     24          // K_DIM / 32
#define NGEMM   496         // T_TOTAL / 64
#define NZERO   240         // 15360 padding rows / 64

typedef __attribute__((ext_vector_type(8))) short    bf16x8;
typedef __attribute__((ext_vector_type(4))) float    f32x4;
typedef __attribute__((ext_vector_type(4))) unsigned u32x4;

__device__ __forceinline__ unsigned short f2bf(float f) {
  unsigned u = __builtin_bit_cast(unsigned, f);
  u += 0x7fffu + ((u >> 16) & 1u);
  return (unsigned short)(u >> 16);
}

__device__ __forceinline__ unsigned cvtpk(float lo, float hi) {
  unsigned r;
  asm("v_cvt_pk_bf16_f32 %0, %1, %2" : "=v"(r) : "v"(lo), "v"(hi));
  return r;
}

// async global->LDS, 16B per lane; LDS dest = wave-uniform base + lane*16
__device__ __forceinline__ void gload16(const void* g, void* l) {
  __builtin_amdgcn_global_load_lds(
      (const __attribute__((address_space(1))) unsigned int*)g,
      (__attribute__((address_space(3))) unsigned int*)l,
      16, 0, 0);
}

// ---------------------------------------------------------------------------
// Kernel 1: W [768][256] f32 -> Wt_tiled bf16 in EXACT per-K-step LDS image
// order: element (kt, h, col, e) = bf16(W[kt*32 + h*8 + e][col]).
// GEMM staging of B is then a contiguous 16KB copy per K-step.
// ---------------------------------------------------------------------------
__global__ __launch_bounds__(256) void wt_tile(const float* __restrict__ W,
                                               unsigned short* __restrict__ Wt) {
  __shared__ float Wl[32][257];     // +1 pad
  const int kt  = blockIdx.x;       // 0..23
  const int tid = threadIdx.x;

#pragma unroll
  for (int i = 0; i < 8; ++i) {
    const int idx = i * 256 + tid;          // 0..2047 chunks of f32x4
    const int row = idx >> 6;
    const int c4  = idx & 63;
    f32x4 v = *(const f32x4*)(W + (size_t)(kt * 32 + row) * N_DIM + c4 * 4);
    Wl[row][c4 * 4 + 0] = v[0];
    Wl[row][c4 * 4 + 1] = v[1];
    Wl[row][c4 * 4 + 2] = v[2];
    Wl[row][c4 * 4 + 3] = v[3];
  }
  __syncthreads();

#pragma unroll
  for (int h = 0; h < 4; ++h) {
    bf16x8 ov;
#pragma unroll
    for (int e = 0; e < 8; ++e) ov[e] = (short)f2bf(Wl[h * 8 + e][tid]);
    *(bf16x8*)(Wt + (((size_t)kt * 4 + h) * 256 + tid) * 8) = ov;
  }
}

// ---------------------------------------------------------------------------
// Kernel 2: GEMM + scatter + fused padding zero-fill.  R8 structure (best:
// 33.6us) with ONE change: B staging is 3-deep and the per-step barrier is a
// raw s_barrier with NO vmcnt drain.  The compiler's auto-wait before
// WRITE_A (must retire the older A global loads; in-order retirement also
// retires B(t+1)) provides the counted wait for free; B(t+2)'s two
// global_load_lds stay in flight ACROSS the barrier (T4).
//   per-step order: LOAD_A(t+1) | STAGE_B(t+2) | COMPUTE(t) | WRITE_A(t+1)
//                   | lgkmcnt(0) | s_barrier
// LDS 56KB (A 2x4KB bf16, B 3x16KB bf16) -> 2 blocks/CU, 16 waves/CU.
// ---------------------------------------------------------------------------
__global__ __launch_bounds__(512, 4) void gemm_scatter(const float* __restrict__ A,
                                                       const unsigned short* __restrict__ Wt,
                                                       const float* __restrict__ bias,
                                                       float* __restrict__ out) {
  const int tid = threadIdx.x;

  // ---------------- fused zero-fill blocks ----------------
  if (blockIdx.x >= NGEMM) {
    const int z  = blockIdx.x - NGEMM;   // 0..239
    const int p0 = z * 64;               // global padding-row index
    int d = 0, c = 0;
    while (d < 15) {
      const int pad = 1920 - 128 * d;
      if (p0 < c + pad) break;
      c += pad; ++d;
    }
    const int len = 1024 + 128 * d;
    const size_t row0 = (size_t)d * MAXLEN + len + (p0 - c);
    float* dst = out + row0 * N_DIM;
    const f32x4 z4 = {0.f, 0.f, 0.f, 0.f};
#pragma unroll
    for (int j = 0; j < 8; ++j)
      *(f32x4*)(dst + (size_t)(j * 512 + tid) * 4) = z4;
    return;
  }

  // ---------------- GEMM blocks ----------------
  __shared__ f32x4 AbV[2][256];    // 2 x 4KB  bf16 A images
  __shared__ f32x4 BbV[3][1024];   // 3 x 16KB bf16 B images

  const int wid  = tid >> 6;
  const int lane = tid & 63;
  const int l15  = lane & 15;
  const int l4   = lane >> 4;
  const int wr   = wid >> 2;     // 0..1  (M half)
  const int wc   = wid & 3;      // 0..3  (N quarter)
  const int t0   = blockIdx.x * 64;

  // which doc does this tile live in (tiles never straddle docs)
  int off = 0, doc = 0;
  while (doc < 15) {
    const int len = 1024 + 128 * doc;
    if (t0 < off + len) break;
    off += len; ++doc;
  }
  const long tgt0 = (long)doc * MAXLEN + (t0 - off);

  // ---- A stage (threads < 256): row = t>>2, g = t&3 ----
  const int rowS = (tid & 255) >> 2;
  const int gS   = tid & 3;
  const float* pA = A + (size_t)(t0 + rowS) * K_DIM + gS * 8;
  const int awbyte = (gS * 64 + (rowS ^ (gS << 1))) * 16;   // XOR-permuted slot

  // ---- B DMA source (contiguous 16KB per K-step) ----
  const unsigned short* pB = Wt + (size_t)tid * 8;

  char* ldsA  = (char*)&AbV[0][0];
  char* ldsB  = (char*)&BbV[0][0];
  char* ldsBw = ldsB + wid * 1024;

  // ---- fragment read offsets ----
  const int arow  = wr * 32 + l15;
  const int aoff0 = l4 * 1024 + ((arow ^ (l4 << 1)) * 16);   // mf=0; mf=1 -> +256
  const int boff  = l4 * 4096 + (wc * 64 + l15) * 16;        // nf -> +nf*256

  f32x4 acc[2][4];
#pragma unroll
  for (int m = 0; m < 2; ++m)
#pragma unroll
    for (int n = 0; n < 4; ++n) acc[m][n] = f32x4{0.f, 0.f, 0.f, 0.f};

#define STAGE_B(buf, kt_)                                                \
  {                                                                      \
    gload16(pB + (size_t)(kt_) * 8192, ldsBw + (buf) * 16384);           \
    gload16(pB + (size_t)(kt_) * 8192 + 4096,                            \
            ldsBw + (buf) * 16384 + 8192);                               \
  }

#define WRITE_A(buf, La0, La1)                                           \
  {                                                                      \
    u32x4 u;                                                             \
    u[0] = cvtpk(La0[0], La0[1]); u[1] = cvtpk(La0[2], La0[3]);          \
    u[2] = cvtpk(La1[0], La1[1]); u[3] = cvtpk(La1[2], La1[3]);          \
    *(u32x4*)(ldsA + (buf) * 4096 + awbyte) = u;                         \
  }

#define COMPUTE(abuf, bbuf)                                              \
  {                                                                      \
    const char* ab = ldsA + (abuf) * 4096;                               \
    const char* bb = ldsB + (bbuf) * 16384 + boff;                       \
    bf16x8 bf0 = *(const bf16x8*)(bb);                                   \
    bf16x8 bf1 = *(const bf16x8*)(bb + 256);                             \
    bf16x8 bf2 = *(const bf16x8*)(bb + 512);                             \
    bf16x8 bf3 = *(const bf16x8*)(bb + 768);                             \
    bf16x8 af0 = *(const bf16x8*)(ab + aoff0);                           \
    bf16x8 af1 = *(const bf16x8*)(ab + aoff0 + 256);                     \
    acc[0][0] = __builtin_amdgcn_mfma_f32_16x16x32_bf16(af0, bf0, acc[0][0], 0, 0, 0); \
    acc[0][1] = __builtin_amdgcn_mfma_f32_16x16x32_bf16(af0, bf1, acc[0][1], 0, 0, 0); \
    acc[0][2] = __builtin_amdgcn_mfma_f32_16x16x32_bf16(af0, bf2, acc[0][2], 0, 0, 0); \
    acc[0][3] = __builtin_amdgcn_mfma_f32_16x16x32_bf16(af0, bf3, acc[0][3], 0, 0, 0); \
    acc[1][0] = __builtin_amdgcn_mfma_f32_16x16x32_bf16(af1, bf0, acc[1][0], 0, 0, 0); \
    acc[1][1] = __builtin_amdgcn_mfma_f32_16x16x32_bf16(af1, bf1, acc[1][1], 0, 0, 0); \
    acc[1][2] = __builtin_amdgcn_mfma_f32_16x16x32_bf16(af1, bf2, acc[1][2], 0, 0, 0); \
    acc[1][3] = __builtin_amdgcn_mfma_f32_16x16x32_bf16(af1, bf3, acc[1][3], 0, 0, 0); \
  }

  // prologue: A loads first (so later auto-waits count them oldest-first),
  // then B tiles 0 and 1; wait B0 only (B1 stays in flight across barrier).
  {
    f32x4 La0, La1;
    if (tid < 256) {
      La0 = *(const f32x4*)(pA);
      La1 = *(const f32x4*)(pA + 4);
    }
    __builtin_amdgcn_sched_barrier(0);
    STAGE_B(0, 0)
    STAGE_B(1, 1)
    __builtin_amdgcn_sched_barrier(0);
    if (tid < 256) WRITE_A(0, La0, La1)
    asm volatile("s_waitcnt vmcnt(2)" ::: "memory");   // B0 landed
    asm volatile("s_waitcnt lgkmcnt(0)" ::: "memory"); // A ds_write done
    __builtin_amdgcn_sched_barrier(0);
    __builtin_amdgcn_s_barrier();
    __builtin_amdgcn_sched_barrier(0);
  }

  // main loop: B(t+2) issued here stays in flight across the barrier; the
  // compiler's auto-wait before WRITE_A retires A(t+1) and (in-order) B(t+1).
#pragma unroll 1
  for (int t = 0; t < NKT - 1; ++t) {
    f32x4 La0, La1;
    if (tid < 256) {
      La0 = *(const f32x4*)(pA + (t + 1) * 32);
      La1 = *(const f32x4*)(pA + (t + 1) * 32 + 4);
    }
    __builtin_amdgcn_sched_barrier(0);
    if (t + 2 < NKT) STAGE_B((t + 2) % 3, t + 2)
    __builtin_amdgcn_sched_barrier(0);
    COMPUTE(t & 1, t % 3)
    if (tid < 256) WRITE_A((t + 1) & 1, La0, La1)
    asm volatile("s_waitcnt lgkmcnt(0)" ::: "memory");
    __builtin_amdgcn_sched_barrier(0);
    __builtin_amdgcn_s_barrier();
    __builtin_amdgcn_sched_barrier(0);
  }
  COMPUTE((NKT - 1) & 1, (NKT - 1) % 3)

  // epilogue: bias + scatter to padded rows
  float bc[4];
#pragma unroll
  for (int n = 0; n < 4; ++n) bc[n] = bias[wc * 64 + n * 16 + l15];

#pragma unroll
  for (int m = 0; m < 2; ++m)
#pragma unroll
    for (int n = 0; n < 4; ++n) {
      const size_t base = (size_t)(tgt0 + wr * 32 + m * 16 + l4 * 4) * N_DIM
                        + wc * 64 + n * 16 + l15;
#pragma unroll
      for (int j = 0; j < 4; ++j)
        out[base + (size_t)j * N_DIM] = acc[m][n][j] + bc[n];
    }
#undef STAGE_B
#undef WRITE_A
#undef COMPUTE
}

// ---------------------------------------------------------------------------
extern "C" void kernel_launch(void* const* d_in, const int* in_sizes, int n_in,
                              void* d_out, int out_size, void* d_ws, size_t ws_size,
                              hipStream_t stream) {
  const float* A    = (const float*)d_in[0];   // [31744, 768]
  const float* W    = (const float*)d_in[1];   // [768, 256]
  const float* bias = (const float*)d_in[2];   // [256]
  float* out = (float*)d_out;                  // [16, 2944, 256]
  unsigned short* Wt = (unsigned short*)d_ws;  // Wt_tiled bf16 [24][4][256][8]

  wt_tile<<<24, 256, 0, stream>>>(W, Wt);
  gemm_scatter<<<NGEMM + NZERO, 512, 0, stream>>>(A, Wt, bias, out);
}

// Round 14
// 33.584 us; speedup vs baseline: 1.3491x; 1.0361x over previous
//
#include <hip/hip_runtime.h>
#include <hip/hip_bf16.h>

// FINAL (revert to round-8 best: 33.6us total).
// Problem constants (fixed by the reference file):
//   B=16 docs, PREV(K)=768, D(N)=256, lengths[i]=1024+128*i, T=31744, MAXLEN=2944
// Doc start offsets are multiples of 128 -> 64-row M-tiles never straddle docs.
// Per-doc padding 1920-128*d is a multiple of 64 -> 64-row zero tiles never straddle.
//
// Session summary (what mattered, evidence-backed):
//  - bf16 MFMA with fp32 accumulate passes the 0.109 threshold (absmax 0.031).
//  - Coalesced staging was the big lever (79->39us): B pre-arranged in exact
//    per-K-step LDS image order (contiguous 16KB DMA via global_load_lds),
//    A reg-staged f32->bf16 (v_cvt_pk_bf16_f32) into XOR-permuted LDS slots.
//  - Structure family optimum: BM=64, BK=32, 512 thr, 2-phase barrier loop,
//    ~2 blocks/CU. Variants tested and REJECTED on-HW: B-direct-from-L2 (R9),
//    3-buf counted-vmcnt (R10), BK=64 (R11), BM=128 one-wave grid (R12),
//    no-drain 3-deep B pipeline (R13) -> all 34-45us. Remaining gap to the
//    ~15us HBM floor is distributed barrier/launch latency, not BW or compute.

#define T_TOTAL 31744
#define K_DIM   768
#define N_DIM   256
#define MAXLEN  2944
#define NKT     24          // K_DIM / 32
#define NGEMM   496         // T_TOTAL / 64
#define NZERO   240         // 15360 padding rows / 64

typedef __attribute__((ext_vector_type(8))) short    bf16x8;
typedef __attribute__((ext_vector_type(4))) float    f32x4;
typedef __attribute__((ext_vector_type(4))) unsigned u32x4;

__device__ __forceinline__ unsigned short f2bf(float f) {
  unsigned u = __builtin_bit_cast(unsigned, f);
  u += 0x7fffu + ((u >> 16) & 1u);
  return (unsigned short)(u >> 16);
}

__device__ __forceinline__ unsigned cvtpk(float lo, float hi) {
  unsigned r;
  asm("v_cvt_pk_bf16_f32 %0, %1, %2" : "=v"(r) : "v"(lo), "v"(hi));
  return r;
}

// async global->LDS, 16B per lane; LDS dest = wave-uniform base + lane*16
__device__ __forceinline__ void gload16(const void* g, void* l) {
  __builtin_amdgcn_global_load_lds(
      (const __attribute__((address_space(1))) unsigned int*)g,
      (__attribute__((address_space(3))) unsigned int*)l,
      16, 0, 0);
}

// ---------------------------------------------------------------------------
// Kernel 1: W [768][256] f32 -> Wt_tiled bf16 in EXACT per-K-step LDS image
// order: element (kt, h, col, e) = bf16(W[kt*32 + h*8 + e][col]).
// GEMM staging of B is then a contiguous 16KB copy per K-step.
// ---------------------------------------------------------------------------
__global__ __launch_bounds__(256) void wt_tile(const float* __restrict__ W,
                                               unsigned short* __restrict__ Wt) {
  __shared__ float Wl[32][257];     // +1 pad
  const int kt  = blockIdx.x;       // 0..23
  const int tid = threadIdx.x;

#pragma unroll
  for (int i = 0; i < 8; ++i) {
    const int idx = i * 256 + tid;          // 0..2047 chunks of f32x4
    const int row = idx >> 6;
    const int c4  = idx & 63;
    f32x4 v = *(const f32x4*)(W + (size_t)(kt * 32 + row) * N_DIM + c4 * 4);
    Wl[row][c4 * 4 + 0] = v[0];
    Wl[row][c4 * 4 + 1] = v[1];
    Wl[row][c4 * 4 + 2] = v[2];
    Wl[row][c4 * 4 + 3] = v[3];
  }
  __syncthreads();

#pragma unroll
  for (int h = 0; h < 4; ++h) {
    bf16x8 ov;
#pragma unroll
    for (int e = 0; e < 8; ++e) ov[e] = (short)f2bf(Wl[h * 8 + e][tid]);
    *(bf16x8*)(Wt + (((size_t)kt * 4 + h) * 256 + tid) * 8) = ov;
  }
}

// ---------------------------------------------------------------------------
// Kernel 2: GEMM + scatter + fused padding zero-fill.
//   blocks [0, NGEMM):    BM=64 GEMM tile, 2-phase pipeline
//   blocks [NGEMM, +240): zero 64 padding rows each (write-only, overlaps)
//
//   A image (4KB/buf, bf16): slot16 = g*64 + (row ^ 2g), g = k-octet.
//       stage (threads<256): row=t>>2, g=t&3; reads 8 consecutive f32
//       (coalesced: 4 threads cover one row's 128B), cvt_pk, one ds_write_b128.
//       write: 2-way banks (free). frag read: 16 lanes hit a permuted
//       contiguous 256B window -> conflict-free.
//   B image (16KB/buf): contiguous DMA copy from Wt_tiled.
// 512 threads = 8 waves (2m x 4n); per-wave 32x64 tile (2x4 frags, acc 32).
// ---------------------------------------------------------------------------
__global__ __launch_bounds__(512, 4) void gemm_scatter(const float* __restrict__ A,
                                                       const unsigned short* __restrict__ Wt,
                                                       const float* __restrict__ bias,
                                                       float* __restrict__ out) {
  const int tid = threadIdx.x;

  // ---------------- fused zero-fill blocks ----------------
  if (blockIdx.x >= NGEMM) {
    const int z  = blockIdx.x - NGEMM;   // 0..239
    const int p0 = z * 64;               // global padding-row index
    int d = 0, c = 0;
    while (d < 15) {
      const int pad = 1920 - 128 * d;
      if (p0 < c + pad) break;
      c += pad; ++d;
    }
    const int len = 1024 + 128 * d;
    const size_t row0 = (size_t)d * MAXLEN + len + (p0 - c);
    float* dst = out + row0 * N_DIM;
    const f32x4 z4 = {0.f, 0.f, 0.f, 0.f};
#pragma unroll
    for (int j = 0; j < 8; ++j)
      *(f32x4*)(dst + (size_t)(j * 512 + tid) * 4) = z4;
    return;
  }

  // ---------------- GEMM blocks ----------------
  __shared__ f32x4 AbV[2][256];    // 2 x 4KB  (bf16 A image)
  __shared__ f32x4 BbV[2][1024];   // 2 x 16KB (bf16 B image)

  const int wid  = tid >> 6;
  const int lane = tid & 63;
  const int l15  = lane & 15;
  const int l4   = lane >> 4;
  const int wr   = wid >> 2;     // 0..1  (M half)
  const int wc   = wid & 3;      // 0..3  (N quarter)
  const int t0   = blockIdx.x * 64;

  // which doc does this tile live in (tiles never straddle docs)
  int off = 0, doc = 0;
  while (doc < 15) {
    const int len = 1024 + 128 * doc;
    if (t0 < off + len) break;
    off += len; ++doc;
  }
  const long tgt0 = (long)doc * MAXLEN + (t0 - off);

  // ---- A stage (threads < 256): row = t>>2, g = t&3 ----
  const int rowS = (tid & 255) >> 2;
  const int gS   = tid & 3;
  const float* pA = A + (size_t)(t0 + rowS) * K_DIM + gS * 8;
  const int awbyte = (gS * 64 + (rowS ^ (gS << 1))) * 16;   // XOR-permuted slot

  // ---- B DMA source (contiguous 16KB per K-step) ----
  const unsigned short* pB = Wt + (size_t)tid * 8;

  char* ldsA  = (char*)&AbV[0][0];
  char* ldsB  = (char*)&BbV[0][0];
  char* ldsBw = ldsB + wid * 1024;

  // ---- fragment read offsets ----
  const int arow  = wr * 32 + l15;
  const int aoff0 = l4 * 1024 + ((arow ^ (l4 << 1)) * 16);   // mf=0; mf=1 -> +256
  const int boff  = l4 * 4096 + (wc * 64 + l15) * 16;        // nf -> +nf*256

  f32x4 acc[2][4];
#pragma unroll
  for (int m = 0; m < 2; ++m)
#pragma unroll
    for (int n = 0; n < 4; ++n) acc[m][n] = f32x4{0.f, 0.f, 0.f, 0.f};

#define STAGE_B(buf, kt_)                                                \
  {                                                                      \
    gload16(pB + (size_t)(kt_) * 8192, ldsBw + (buf) * 16384);           \
    gload16(pB + (size_t)(kt_) * 8192 + 4096,                            \
            ldsBw + (buf) * 16384 + 8192);                               \
  }

#define WRITE_A(buf, La0, La1)                                           \
  {                                                                      \
    u32x4 u;                                                             \
    u[0] = cvtpk(La0[0], La0[1]); u[1] = cvtpk(La0[2], La0[3]);          \
    u[2] = cvtpk(La1[0], La1[1]); u[3] = cvtpk(La1[2], La1[3]);          \
    *(u32x4*)(ldsA + (buf) * 4096 + awbyte) = u;                         \
  }

#define COMPUTE(buf)                                                     \
  {                                                                      \
    const char* ab = ldsA + (buf) * 4096;                                \
    const char* bb = ldsB + (buf) * 16384 + boff;                        \
    bf16x8 bf0 = *(const bf16x8*)(bb);                                   \
    bf16x8 bf1 = *(const bf16x8*)(bb + 256);                             \
    bf16x8 bf2 = *(const bf16x8*)(bb + 512);                             \
    bf16x8 bf3 = *(const bf16x8*)(bb + 768);                             \
    bf16x8 af0 = *(const bf16x8*)(ab + aoff0);                           \
    bf16x8 af1 = *(const bf16x8*)(ab + aoff0 + 256);                     \
    acc[0][0] = __builtin_amdgcn_mfma_f32_16x16x32_bf16(af0, bf0, acc[0][0], 0, 0, 0); \
    acc[0][1] = __builtin_amdgcn_mfma_f32_16x16x32_bf16(af0, bf1, acc[0][1], 0, 0, 0); \
    acc[0][2] = __builtin_amdgcn_mfma_f32_16x16x32_bf16(af0, bf2, acc[0][2], 0, 0, 0); \
    acc[0][3] = __builtin_amdgcn_mfma_f32_16x16x32_bf16(af0, bf3, acc[0][3], 0, 0, 0); \
    acc[1][0] = __builtin_amdgcn_mfma_f32_16x16x32_bf16(af1, bf0, acc[1][0], 0, 0, 0); \
    acc[1][1] = __builtin_amdgcn_mfma_f32_16x16x32_bf16(af1, bf1, acc[1][1], 0, 0, 0); \
    acc[1][2] = __builtin_amdgcn_mfma_f32_16x16x32_bf16(af1, bf2, acc[1][2], 0, 0, 0); \
    acc[1][3] = __builtin_amdgcn_mfma_f32_16x16x32_bf16(af1, bf3, acc[1][3], 0, 0, 0); \
  }

  // prologue: stage tile 0 (A via regs, B via DMA), barrier
  if (tid < 256) {
    f32x4 La0 = *(const f32x4*)(pA);
    f32x4 La1 = *(const f32x4*)(pA + 4);
    WRITE_A(0, La0, La1)
  }
  STAGE_B(0, 0)
  __syncthreads();

  // main loop: issue A loads(t+1) early, B DMA(t+1), compute(t), write A(t+1)
#pragma unroll 1
  for (int t = 0; t < NKT - 1; ++t) {
    f32x4 La0, La1;
    if (tid < 256) {
      La0 = *(const f32x4*)(pA + (t + 1) * 32);
      La1 = *(const f32x4*)(pA + (t + 1) * 32 + 4);
    }
    STAGE_B((t + 1) & 1, t + 1)
    COMPUTE(t & 1)
    if (tid < 256) WRITE_A((t + 1) & 1, La0, La1)
    __syncthreads();
  }
  COMPUTE((NKT - 1) & 1)

  // epilogue: bias + scatter to padded rows
  float bc[4];
#pragma unroll
  for (int n = 0; n < 4; ++n) bc[n] = bias[wc * 64 + n * 16 + l15];

#pragma unroll
  for (int m = 0; m < 2; ++m)
#pragma unroll
    for (int n = 0; n < 4; ++n) {
      const size_t base = (size_t)(tgt0 + wr * 32 + m * 16 + l4 * 4) * N_DIM
                        + wc * 64 + n * 16 + l15;
#pragma unroll
      for (int j = 0; j < 4; ++j)
        out[base + (size_t)j * N_DIM] = acc[m][n][j] + bc[n];
    }
#undef STAGE_B
#undef WRITE_A
#undef COMPUTE
}

// ---------------------------------------------------------------------------
extern "C" void kernel_launch(void* const* d_in, const int* in_sizes, int n_in,
                              void* d_out, int out_size, void* d_ws, size_t ws_size,
                              hipStream_t stream) {
  const float* A    = (const float*)d_in[0];   // [31744, 768]
  const float* W    = (const float*)d_in[1];   // [768, 256]
  const float* bias = (const float*)d_in[2];   // [256]
  float* out = (float*)d_out;                  // [16, 2944, 256]
  unsigned short* Wt = (unsigned short*)d_ws;  // Wt_tiled bf16 [24][4][256][8]

  wt_tile<<<24, 256, 0, stream>>>(W, Wt);
  gemm_scatter<<<NGEMM + NZERO, 512, 0, stream>>>(A, Wt, bias, out);
}